// Round 13
// baseline (772.871 us; speedup 1.0000x reference)
//
#include <hip/hip_runtime.h>
#include <math.h>

#define NODES 30000
#define NEDGE 480000
#define ETOT  (NODES + NEDGE)
#define NGRAPH 30
#define DIN 256
#define DH 64
#define CAP 128

typedef __bf16 bf16x8 __attribute__((ext_vector_type(8)));
typedef float  f32x4  __attribute__((ext_vector_type(4)));

static __device__ __forceinline__ float elu_f(float x){ return x > 0.f ? x : expm1f(x); }
static __device__ __forceinline__ float bf_lo(unsigned v){ return __uint_as_float(v << 16); }
static __device__ __forceinline__ float bf_hi(unsigned v){ return __uint_as_float(v & 0xffff0000u); }
static __device__ __forceinline__ unsigned pack_bf2(float a, float b){
  __bf16 ob[2] = {(__bf16)a, (__bf16)b};
  return *(unsigned*)ob;
}
static __device__ __forceinline__ void load_lds16(const __bf16* g, __bf16* l){
  __builtin_amdgcn_global_load_lds(
      (const __attribute__((address_space(1))) void*)g,
      (__attribute__((address_space(3))) void*)l, 16, 0, 0);
}

// ---------------- CSR: scan + fill (count fused into k_prep) ----------------
__global__ void k_scan(const int* __restrict__ deg, int* __restrict__ rowptr){
  __shared__ int s[1024];
  int t = threadIdx.x;
  const int CH = (NODES + 1023) / 1024;
  int base = t * CH;
  int local = 0;
  for (int i = 0; i < CH; i++){ int idx = base + i; if (idx < NODES) local += deg[idx]; }
  s[t] = local; __syncthreads();
  for (int off = 1; off < 1024; off <<= 1){
    int v = (t >= off) ? s[t - off] : 0;
    __syncthreads();
    s[t] += v;
    __syncthreads();
  }
  int run = s[t] - local;
  for (int i = 0; i < CH; i++){
    int idx = base + i;
    if (idx < NODES){ rowptr[idx] = run; run += deg[idx]; }
  }
  if (t == 1023) rowptr[NODES] = s[1023];
}

__global__ void k_fill(const int* __restrict__ ei, const int* __restrict__ rowptr,
                       int* __restrict__ cursor, int* __restrict__ colA){
  int e = blockIdx.x*256 + threadIdx.x;
  if (e >= ETOT) return;
  int src, dst;
  if (e < NEDGE){ src = ei[e]; dst = ei[NEDGE + e]; }
  else          { src = e - NEDGE; dst = src; }
  int pos = atomicAdd(&cursor[dst], 1);
  colA[rowptr[dst] + pos] = src;
}

// ---------------- fused: input cast + weight transposes + edge degree count ----------------
#define NCAST4 (NODES*DIN/4)
#define TW0 (512*256)
#define TW1 (512*512)
#define TW2 (64*512)
#define PREPW (NCAST4 + TW0 + TW1 + TW2)
__global__ void k_prep(const float* __restrict__ x, __bf16* __restrict__ xb0,
                       const float* __restrict__ W0, const float* __restrict__ W1,
                       const float* __restrict__ W2, __bf16* __restrict__ Wt0,
                       __bf16* __restrict__ Wt1, __bf16* __restrict__ Wt2,
                       const int* __restrict__ ei, int* __restrict__ deg){
  int idx = blockIdx.x*256 + threadIdx.x;
  if (idx < NCAST4){
    float4 v = ((const float4*)x)[idx];
    __bf16 o[4] = {(__bf16)v.x, (__bf16)v.y, (__bf16)v.z, (__bf16)v.w};
    *(uint2*)(xb0 + (size_t)idx*4) = *(const uint2*)o;
    return;
  }
  int j = idx - NCAST4;
  if (j < TW0){
    int n = j >> 8, k = j & 255;
    Wt0[j] = (__bf16)W0[(size_t)k*512 + n];
    return;
  }
  j -= TW0;
  if (j < TW1){
    int n = j >> 9, k = j & 511;
    Wt1[j] = (__bf16)W1[(size_t)k*512 + n];
    return;
  }
  j -= TW1;
  if (j < TW2){
    int n = j >> 9, k = j & 511;
    Wt2[j] = (__bf16)W2[(size_t)k*64 + n];
    return;
  }
  j -= TW2;
  if (j < ETOT){
    int dst = (j < NEDGE) ? ei[NEDGE + j] : (j - NEDGE);
    atomicAdd(&deg[dst], 1);
  }
}

// ---------------- bf16 MFMA GEMM (global_load_lds staging) + fused attention scores ----------------
__global__ __launch_bounds__(256) void k_gemm_bf16(const __bf16* __restrict__ A,
    const __bf16* __restrict__ Bt, __bf16* __restrict__ C,
    const float* __restrict__ asrc, const float* __restrict__ adst,
    float* __restrict__ ssrc, float* __restrict__ sdst, int heads,
    int M, int N, int K){
  __shared__ __align__(16) __bf16 As[128*64];
  __shared__ __align__(16) __bf16 Bs[128*64];
  int tid  = threadIdx.x;
  int lane = tid & 63, wave = tid >> 6;
  int wr = wave >> 1, wc = wave & 1;
  int q = lane >> 4, r = lane & 15;
  int rowBase = blockIdx.y * 128, colBase = blockIdx.x * 128;
  f32x4 acc[4][4] = {};
  for (int k0 = 0; k0 < K; k0 += 64){
    #pragma unroll
    for (int p = 0; p < 4; p++){
      int lin = p*256 + tid;
      int rr = lin >> 3, ko = (lin & 7) * 8;
      int gr = rowBase + rr; if (gr >= M) gr = M - 1;
      load_lds16(A + (size_t)gr*K + k0 + ko, As + lin*8);
      int gn = colBase + rr; if (gn >= N) gn = N - 1;
      load_lds16(Bt + (size_t)gn*K + k0 + ko, Bs + lin*8);
    }
    __syncthreads();
    #pragma unroll
    for (int kk = 0; kk < 2; kk++){
      bf16x8 af[4], bfr[4];
      #pragma unroll
      for (int i = 0; i < 4; i++) af[i]  = *(const bf16x8*)(&As[(wr*64 + i*16 + r)*64 + kk*32 + q*8]);
      #pragma unroll
      for (int j = 0; j < 4; j++) bfr[j] = *(const bf16x8*)(&Bs[(wc*64 + j*16 + r)*64 + kk*32 + q*8]);
      #pragma unroll
      for (int i = 0; i < 4; i++)
        #pragma unroll
        for (int j = 0; j < 4; j++)
          acc[i][j] = __builtin_amdgcn_mfma_f32_16x16x32_bf16(af[i], bfr[j], acc[i][j], 0, 0, 0);
    }
    __syncthreads();
  }
  #pragma unroll
  for (int i = 0; i < 4; i++){
    #pragma unroll
    for (int j = 0; j < 4; j++){
      int col = colBase + wc*64 + j*16 + r;
      if (col >= N) continue;
      #pragma unroll
      for (int v = 0; v < 4; v++){
        int row = rowBase + wr*64 + i*16 + q*4 + v;
        if (row < M) C[(size_t)row*N + col] = (__bf16)acc[i][j][v];
      }
    }
  }
  // fused attention scores
  int colW = colBase + wc*64;
  if (colW < N){
    int hb = colW >> 6;
    float a_s[4], a_d[4];
    #pragma unroll
    for (int j = 0; j < 4; j++){
      a_s[j] = asrc[hb*64 + j*16 + r];
      a_d[j] = adst[hb*64 + j*16 + r];
    }
    #pragma unroll
    for (int i = 0; i < 4; i++){
      #pragma unroll
      for (int v = 0; v < 4; v++){
        float s1 = 0.f, s2 = 0.f;
        #pragma unroll
        for (int j = 0; j < 4; j++){
          float av = acc[i][j][v];
          s1 += av * a_s[j];
          s2 += av * a_d[j];
        }
        #pragma unroll
        for (int off = 1; off < 16; off <<= 1){
          s1 += __shfl_xor(s1, off, 64);
          s2 += __shfl_xor(s2, off, 64);
        }
        if (r == 0){
          int row = rowBase + wr*64 + i*16 + q*4 + v;
          if (row < M){
            ssrc[(size_t)row*heads + hb] = s1;
            sdst[(size_t)row*heads + hb] = s2;
          }
        }
      }
    }
  }
}

// ---------------- GAT aggregation, 8 heads; 512 threads: 8 edge-waves, softmax 1 wave/head ----------------
__global__ __launch_bounds__(512) void k_gatagg8(const __bf16* __restrict__ hb,
    const float* __restrict__ ssrc, const float* __restrict__ sdst,
    const int* __restrict__ rowptr, const int* __restrict__ colA,
    const float* __restrict__ bias, __bf16* __restrict__ outb){
  int n = blockIdx.x;
  int t = threadIdx.x;
  __shared__ int ecol[CAP];
  __shared__ float p[CAP][9];
  __shared__ float racc[7][8][64];
  __shared__ float dhv[8], sdsh[8], mh[8];
  int base = rowptr[n];
  int deg = rowptr[n+1] - base;
  if (t < 8) sdsh[t] = sdst[(size_t)n*8 + t];
  __syncthreads();
  int w = t >> 6, l = t & 63;
  int f8 = l * 8;
  int hh = l >> 3;
  if (deg <= CAP){
    if (t < deg){
      int c = colA[base + t];
      ecol[t] = c;
      const float4* sp = (const float4*)(ssrc + (size_t)c*8);
      float4 s0 = sp[0], s1 = sp[1];
      float v;
      v = s0.x + sdsh[0]; p[t][0] = v > 0.f ? v : 0.2f*v;
      v = s0.y + sdsh[1]; p[t][1] = v > 0.f ? v : 0.2f*v;
      v = s0.z + sdsh[2]; p[t][2] = v > 0.f ? v : 0.2f*v;
      v = s0.w + sdsh[3]; p[t][3] = v > 0.f ? v : 0.2f*v;
      v = s1.x + sdsh[4]; p[t][4] = v > 0.f ? v : 0.2f*v;
      v = s1.y + sdsh[5]; p[t][5] = v > 0.f ? v : 0.2f*v;
      v = s1.z + sdsh[6]; p[t][6] = v > 0.f ? v : 0.2f*v;
      v = s1.w + sdsh[7]; p[t][7] = v > 0.f ? v : 0.2f*v;
    }
    __syncthreads();
    // softmax: wave w owns head w, 64 lanes over edges
    {
      float m = -1e30f;
      for (int e = l; e < deg; e += 64) m = fmaxf(m, p[e][w]);
      #pragma unroll
      for (int off = 1; off < 64; off <<= 1) m = fmaxf(m, __shfl_xor(m, off, 64));
      float d = 0.f;
      for (int e = l; e < deg; e += 64){ float xv = __expf(p[e][w] - m); p[e][w] = xv; d += xv; }
      #pragma unroll
      for (int off = 1; off < 64; off <<= 1) d += __shfl_xor(d, off, 64);
      if (l == 0) dhv[w] = 1.f / (d + 1e-16f);
    }
    __syncthreads();
    // gather: wave w takes edges w, w+8, ...; each lane owns 8 feats (uint4)
    float a0[8] = {}, a1[8] = {};
    int e = w;
    for (; e + 8 < deg; e += 16){
      int c0 = ecol[e], c1 = ecol[e+8];
      float p0 = p[e][hh], p1 = p[e+8][hh];
      uint4 v0 = *(const uint4*)(hb + (size_t)c0*512 + f8);
      uint4 v1 = *(const uint4*)(hb + (size_t)c1*512 + f8);
      unsigned w0[4] = {v0.x, v0.y, v0.z, v0.w};
      unsigned w1[4] = {v1.x, v1.y, v1.z, v1.w};
      #pragma unroll
      for (int j = 0; j < 4; j++){
        a0[2*j]   += p0*bf_lo(w0[j]); a0[2*j+1] += p0*bf_hi(w0[j]);
        a1[2*j]   += p1*bf_lo(w1[j]); a1[2*j+1] += p1*bf_hi(w1[j]);
      }
    }
    for (; e < deg; e += 8){
      float pe = p[e][hh];
      uint4 v = *(const uint4*)(hb + (size_t)ecol[e]*512 + f8);
      unsigned ww[4] = {v.x, v.y, v.z, v.w};
      #pragma unroll
      for (int j = 0; j < 4; j++){
        a0[2*j] += pe*bf_lo(ww[j]); a0[2*j+1] += pe*bf_hi(ww[j]);
      }
    }
    #pragma unroll
    for (int j = 0; j < 8; j++) a0[j] += a1[j];
    if (w){
      #pragma unroll
      for (int j = 0; j < 8; j++) racc[w-1][j][l] = a0[j];
    }
    __syncthreads();
    if (w == 0){
      float rcp = dhv[hh];
      float4 bb0 = *(const float4*)(bias + f8);
      float4 bb1 = *(const float4*)(bias + f8 + 4);
      float bb[8] = {bb0.x, bb0.y, bb0.z, bb0.w, bb1.x, bb1.y, bb1.z, bb1.w};
      __bf16 ob[8];
      #pragma unroll
      for (int j = 0; j < 8; j++){
        float s = a0[j];
        #pragma unroll
        for (int k = 0; k < 7; k++) s += racc[k][j][l];
        ob[j] = (__bf16)(s*rcp + bb[j]);
      }
      *(uint4*)(outb + (size_t)n*512 + f8) = *(const uint4*)ob;
    }
  } else {
    // slow path (deg > CAP; statistically never hit)
    float m = -1e30f;
    for (int e = l; e < deg; e += 64){
      int c = colA[base + e];
      float sc = ssrc[(size_t)c*8 + w] + sdsh[w];
      sc = sc > 0.f ? sc : 0.2f*sc;
      m = fmaxf(m, sc);
    }
    #pragma unroll
    for (int off = 1; off < 64; off <<= 1) m = fmaxf(m, __shfl_xor(m, off, 64));
    if (l == 0) mh[w] = m;
    __syncthreads();
    float d = 0.f;
    float mm = mh[w];
    for (int e = l; e < deg; e += 64){
      int c = colA[base + e];
      float sc = ssrc[(size_t)c*8 + w] + sdsh[w];
      sc = sc > 0.f ? sc : 0.2f*sc;
      d += __expf(sc - mm);
    }
    #pragma unroll
    for (int off = 1; off < 64; off <<= 1) d += __shfl_xor(d, off, 64);
    if (l == 0) dhv[w] = 1.f / (d + 1e-16f);
    __syncthreads();
    float a0[8] = {};
    float mhh = mh[hh];
    float sdd = sdsh[hh];
    for (int e = w; e < deg; e += 8){
      int c = colA[base + e];
      float sc = ssrc[(size_t)c*8 + hh] + sdd;
      sc = sc > 0.f ? sc : 0.2f*sc;
      float pe = __expf(sc - mhh);
      uint4 v = *(const uint4*)(hb + (size_t)c*512 + f8);
      unsigned ww[4] = {v.x, v.y, v.z, v.w};
      #pragma unroll
      for (int j = 0; j < 4; j++){
        a0[2*j] += pe*bf_lo(ww[j]); a0[2*j+1] += pe*bf_hi(ww[j]);
      }
    }
    if (w){
      #pragma unroll
      for (int j = 0; j < 8; j++) racc[w-1][j][l] = a0[j];
    }
    __syncthreads();
    if (w == 0){
      float rcp = dhv[hh];
      float4 bb0 = *(const float4*)(bias + f8);
      float4 bb1 = *(const float4*)(bias + f8 + 4);
      float bb[8] = {bb0.x, bb0.y, bb0.z, bb0.w, bb1.x, bb1.y, bb1.z, bb1.w};
      __bf16 ob[8];
      #pragma unroll
      for (int j = 0; j < 8; j++){
        float s = a0[j];
        #pragma unroll
        for (int k = 0; k < 7; k++) s += racc[k][j][l];
        ob[j] = (__bf16)(s*rcp + bb[j]);
      }
      *(uint4*)(outb + (size_t)n*512 + f8) = *(const uint4*)ob;
    }
  }
}

// ---------------- GAT aggregation, 1 head (F=64), bf16 in/out, unroll-2 ----------------
__global__ __launch_bounds__(256) void k_gatagg1(const __bf16* __restrict__ hb,
    const float* __restrict__ ssrc, const float* __restrict__ sdst,
    const int* __restrict__ rowptr, const int* __restrict__ colA,
    const float* __restrict__ bias, __bf16* __restrict__ outb){
  int n = blockIdx.x;
  int t = threadIdx.x;
  __shared__ int ecol[CAP];
  __shared__ float p[CAP];
  __shared__ float racc[8][64];
  __shared__ float dhv1, mh1, sds;
  int base = rowptr[n];
  int deg = rowptr[n+1] - base;
  if (t == 0) sds = sdst[n];
  __syncthreads();
  int g = t >> 5, l = t & 31;
  if (deg <= CAP){
    if (t < deg){
      int c = colA[base + t];
      ecol[t] = c;
      float sc = ssrc[c] + sds;
      p[t] = sc > 0.f ? sc : 0.2f*sc;
    }
    __syncthreads();
    if (t < 64){
      float m = -1e30f;
      for (int e = t; e < deg; e += 64) m = fmaxf(m, p[e]);
      #pragma unroll
      for (int off = 1; off < 64; off <<= 1) m = fmaxf(m, __shfl_xor(m, off, 64));
      float d = 0.f;
      for (int e = t; e < deg; e += 64){ float xv = __expf(p[e] - m); p[e] = xv; d += xv; }
      #pragma unroll
      for (int off = 1; off < 64; off <<= 1) d += __shfl_xor(d, off, 64);
      if (t == 0) dhv1 = 1.f / (d + 1e-16f);
    }
    __syncthreads();
    float a0 = 0.f, a1 = 0.f, b0v = 0.f, b1v = 0.f;
    int e = g;
    for (; e + 8 < deg; e += 16){
      int c0 = ecol[e], c1 = ecol[e+8];
      float pe0 = p[e], pe1 = p[e+8];
      unsigned v0 = *(const unsigned*)(hb + (size_t)c0*64 + l*2);
      unsigned v1 = *(const unsigned*)(hb + (size_t)c1*64 + l*2);
      a0  += pe0*bf_lo(v0); a1  += pe0*bf_hi(v0);
      b0v += pe1*bf_lo(v1); b1v += pe1*bf_hi(v1);
    }
    for (; e < deg; e += 8){
      float pe = p[e];
      unsigned v = *(const unsigned*)(hb + (size_t)ecol[e]*64 + l*2);
      a0 += pe*bf_lo(v); a1 += pe*bf_hi(v);
    }
    a0 += b0v; a1 += b1v;
    racc[g][l*2] = a0; racc[g][l*2+1] = a1;
    __syncthreads();
    if (t < 32){
      float s0 = 0.f, s1 = 0.f;
      #pragma unroll
      for (int g2 = 0; g2 < 8; g2++){ s0 += racc[g2][t*2]; s1 += racc[g2][t*2+1]; }
      float rcp = dhv1;
      float o0 = s0*rcp + bias[t*2], o1 = s1*rcp + bias[t*2+1];
      *(unsigned*)(outb + (size_t)n*64 + t*2) = pack_bf2(o0, o1);
    }
  } else {
    if (t < 64){
      float m = -1e30f;
      for (int e = t; e < deg; e += 64){
        int c = colA[base + e];
        float sc = ssrc[c] + sds;
        sc = sc > 0.f ? sc : 0.2f*sc;
        m = fmaxf(m, sc);
      }
      #pragma unroll
      for (int off = 1; off < 64; off <<= 1) m = fmaxf(m, __shfl_xor(m, off, 64));
      if (t == 0) mh1 = m;
    }
    __syncthreads();
    if (t < 64){
      float d = 0.f;
      for (int e = t; e < deg; e += 64){
        int c = colA[base + e];
        float sc = ssrc[c] + sds;
        sc = sc > 0.f ? sc : 0.2f*sc;
        d += __expf(sc - mh1);
      }
      #pragma unroll
      for (int off = 1; off < 64; off <<= 1) d += __shfl_xor(d, off, 64);
      if (t == 0) dhv1 = 1.f / (d + 1e-16f);
    }
    __syncthreads();
    float a0 = 0.f, a1 = 0.f;
    float mm = mh1;
    for (int e = g; e < deg; e += 8){
      int c = colA[base + e];
      float sc = ssrc[c] + sds;
      sc = sc > 0.f ? sc : 0.2f*sc;
      float pe = __expf(sc - mm);
      unsigned v = *(const unsigned*)(hb + (size_t)c*64 + l*2);
      a0 += pe*bf_lo(v); a1 += pe*bf_hi(v);
    }
    racc[g][l*2] = a0; racc[g][l*2+1] = a1;
    __syncthreads();
    if (t < 32){
      float s0 = 0.f, s1 = 0.f;
      #pragma unroll
      for (int g2 = 0; g2 < 8; g2++){ s0 += racc[g2][t*2]; s1 += racc[g2][t*2+1]; }
      float rcp = dhv1;
      float o0 = s0*rcp + bias[t*2], o1 = s1*rcp + bias[t*2+1];
      *(unsigned*)(outb + (size_t)n*64 + t*2) = pack_bf2(o0, o1);
    }
  }
}

// ---------------- BatchNorm stats, two-stage, NO atomics ----------------
__global__ __launch_bounds__(256) void k_bnstat1(const __bf16* __restrict__ xb,
    float* __restrict__ partial, int F){
  int t = threadIdx.x;
  int OCT = F >> 3;
  int RPB = 256 / OCT;
  int o = t & (OCT - 1), r = t / OCT;
  int NB = gridDim.x;
  float s[8] = {}, q[8] = {};
  int step = NB * RPB;
  for (int n = blockIdx.x*RPB + r; n < NODES; n += step){
    uint4 v = *(const uint4*)(xb + (size_t)n*F + o*8);
    unsigned vv[4] = {v.x, v.y, v.z, v.w};
    #pragma unroll
    for (int j = 0; j < 4; j++){
      float lo = bf_lo(vv[j]), hi = bf_hi(vv[j]);
      s[2*j]   += lo; q[2*j]   += lo*lo;
      s[2*j+1] += hi; q[2*j+1] += hi*hi;
    }
  }
  __shared__ float red[256][17];
  #pragma unroll
  for (int j = 0; j < 8; j++){ red[t][j] = s[j]; red[t][8+j] = q[j]; }
  __syncthreads();
  for (int st = RPB >> 1; st > 0; st >>= 1){
    if (r < st){
      #pragma unroll
      for (int j = 0; j < 16; j++) red[t][j] += red[t + st*OCT][j];
    }
    __syncthreads();
  }
  if (r == 0){
    #pragma unroll
    for (int j = 0; j < 8; j++){
      partial[(size_t)(o*8 + j)*NB + blockIdx.x]     = red[t][j];
      partial[(size_t)(F + o*8 + j)*NB + blockIdx.x] = red[t][8 + j];
    }
  }
}

__global__ void k_bnstat2(const float* __restrict__ partial, float* __restrict__ sum,
                          float* __restrict__ sumsq, int F, int NB){
  int row = blockIdx.x;
  int t = threadIdx.x;
  float a = 0.f;
  for (int i = t; i < NB; i += 64) a += partial[(size_t)row*NB + i];
  #pragma unroll
  for (int off = 1; off < 64; off <<= 1) a += __shfl_xor(a, off, 64);
  if (t == 0){
    if (row < F) sum[row] = a;
    else         sumsq[row - F] = a;
  }
}

// ---------------- BN(inline) + ELU + optional residual, bf16->bf16, uint4 ----------------
__global__ __launch_bounds__(256) void k_bnapply_b(const __bf16* __restrict__ xb,
    const float* __restrict__ sum, const float* __restrict__ sumsq,
    const float* __restrict__ g, const float* __restrict__ b,
    const __bf16* __restrict__ res, __bf16* __restrict__ y, int rows){
  int t = threadIdx.x;
  int o8 = (t & 63) * 8;
  int rw = t >> 6;
  float sm[8], sq[8], gg[8], bb[8];
  *(float4*)sm     = *(const float4*)(sum + o8);
  *(float4*)(sm+4) = *(const float4*)(sum + o8 + 4);
  *(float4*)sq     = *(const float4*)(sumsq + o8);
  *(float4*)(sq+4) = *(const float4*)(sumsq + o8 + 4);
  *(float4*)gg     = *(const float4*)(g + o8);
  *(float4*)(gg+4) = *(const float4*)(g + o8 + 4);
  *(float4*)bb     = *(const float4*)(b + o8);
  *(float4*)(bb+4) = *(const float4*)(b + o8 + 4);
  const float inv_n = 1.f / (float)NODES;
  float sc[8], sh[8];
  #pragma unroll
  for (int j = 0; j < 8; j++){
    float m = sm[j]*inv_n;
    float v = sq[j]*inv_n - m*m;
    sc[j] = gg[j]*rsqrtf(v + 1e-5f);
    sh[j] = bb[j] - m*sc[j];
  }
  int nend = min(blockIdx.x*rows + rows, NODES);
  for (int n = blockIdx.x*rows + rw; n < nend; n += 4){
    size_t off = (size_t)n*512 + o8;
    uint4 v = *(const uint4*)(xb + off);
    unsigned w[4] = {v.x, v.y, v.z, v.w};
    float ov[8];
    #pragma unroll
    for (int j = 0; j < 4; j++){
      ov[2*j]   = elu_f(bf_lo(w[j])*sc[2*j]   + sh[2*j]);
      ov[2*j+1] = elu_f(bf_hi(w[j])*sc[2*j+1] + sh[2*j+1]);
    }
    if (res){
      uint4 rv = *(const uint4*)(res + off);
      unsigned rw4[4] = {rv.x, rv.y, rv.z, rv.w};
      #pragma unroll
      for (int j = 0; j < 4; j++){
        ov[2*j] += bf_lo(rw4[j]); ov[2*j+1] += bf_hi(rw4[j]);
      }
    }
    __bf16 ob[8];
    #pragma unroll
    for (int j = 0; j < 8; j++) ob[j] = (__bf16)ov[j];
    *(uint4*)(y + off) = *(const uint4*)ob;
  }
}

// ---------------- BN + ELU + LayerNorm (F=64) + fused graph-pool accumulation ----------------
// block = 8 nodes x 32 lanes; per-graph partial sums via LDS, one atomic set per block
__global__ void k_bn_elu_ln_pool(const __bf16* __restrict__ xb, const float* __restrict__ sum,
    const float* __restrict__ sumsq, const float* __restrict__ g, const float* __restrict__ b,
    const float* __restrict__ lg, const float* __restrict__ lb,
    const int* __restrict__ batch, float* __restrict__ pooled){
  int t = threadIdx.x;
  int l = t & 31, sub = t >> 5;
  int n = blockIdx.x*8 + sub;
  float2 sm = *(const float2*)(sum + l*2);
  float2 sq = *(const float2*)(sumsq + l*2);
  float2 gg = *(const float2*)(g + l*2);
  float2 bb = *(const float2*)(b + l*2);
  const float inv_n = 1.f / (float)NODES;
  float m0 = sm.x*inv_n, m1 = sm.y*inv_n;
  float va0 = sq.x*inv_n - m0*m0, va1 = sq.y*inv_n - m1*m1;
  float sc0 = gg.x * rsqrtf(va0 + 1e-5f), sc1 = gg.y * rsqrtf(va1 + 1e-5f);
  float sh0 = bb.x - m0*sc0, sh1 = bb.y - m1*sc1;
  unsigned v = *(const unsigned*)(xb + (size_t)n*64 + l*2);
  float x0 = elu_f(bf_lo(v)*sc0 + sh0);
  float x1 = elu_f(bf_hi(v)*sc1 + sh1);
  float s = x0 + x1;
  #pragma unroll
  for (int off = 1; off < 32; off <<= 1) s += __shfl_xor(s, off, 64);
  float mean = s * (1.f/64.f);
  float d0 = x0 - mean, d1 = x1 - mean;
  float qq = d0*d0 + d1*d1;
  #pragma unroll
  for (int off = 1; off < 32; off <<= 1) qq += __shfl_xor(qq, off, 64);
  float var = qq * (1.f/64.f);
  float inv = rsqrtf(var + 1e-5f);
  float o0 = d0*inv*lg[l*2] + lb[l*2];
  float o1 = d1*inv*lg[l*2+1] + lb[l*2+1];
  __shared__ float sv[8][64];
  __shared__ int gid[8];
  sv[sub][l*2] = o0; sv[sub][l*2+1] = o1;
  if (l == 0) gid[sub] = batch[n];
  __syncthreads();
  if (t < 64){
    int g0 = gid[0];
    if (gid[7] == g0){
      float acc = 0.f;
      #pragma unroll
      for (int r = 0; r < 8; r++) acc += sv[r][t];
      atomicAdd(&pooled[g0*64 + t], acc);
    } else {
      #pragma unroll
      for (int r = 0; r < 8; r++) atomicAdd(&pooled[gid[r]*64 + t], sv[r][t]);
    }
  }
}

// ---------------- MLP head + log_softmax (divides pooled sums by counts) ----------------
static __device__ int lbound(const int* a, int n, int v){
  int lo = 0, hi = n;
  while (lo < hi){ int mid = (lo + hi) >> 1; if (a[mid] < v) lo = mid + 1; else hi = mid; }
  return lo;
}

__global__ void k_head(const float* __restrict__ pooled, const int* __restrict__ batch,
                       const float* __restrict__ w1, const float* __restrict__ b1,
                       const float* __restrict__ w2, const float* __restrict__ b2,
                       float* __restrict__ out){
  int g = threadIdx.x;
  if (g >= NGRAPH) return;
  int lo = lbound(batch, NODES, g);
  int hi = lbound(batch, NODES, g+1);
  float inv_cnt = 1.f / fmaxf((float)(hi - lo), 1.f);
  float pd[64];
  for (int d = 0; d < 64; d++) pd[d] = pooled[g*DH + d] * inv_cnt;
  float hdd[32];
  for (int j = 0; j < 32; j++){
    float s = b1[j];
    for (int d = 0; d < DH; d++) s += pd[d]*w1[d*32 + j];
    hdd[j] = elu_f(s);
  }
  float l0 = b2[0], l1 = b2[1];
  for (int j = 0; j < 32; j++){ l0 += hdd[j]*w2[j*2]; l1 += hdd[j]*w2[j*2 + 1]; }
  float m = fmaxf(l0, l1);
  float lse = m + logf(expf(l0 - m) + expf(l1 - m));
  out[g*2]     = l0 - lse;
  out[g*2 + 1] = l1 - lse;
}

extern "C" void kernel_launch(void* const* d_in, const int* in_sizes, int n_in,
                              void* d_out, int out_size, void* d_ws, size_t ws_size,
                              hipStream_t stream){
  const float* x    = (const float*)d_in[0];
  const int*   ei   = (const int*)d_in[1];
  const int*   batch= (const int*)d_in[2];
  const float* W0   = (const float*)d_in[3];
  const float* as0  = (const float*)d_in[4];
  const float* ad0  = (const float*)d_in[5];
  const float* b0   = (const float*)d_in[6];
  const float* W1   = (const float*)d_in[7];
  const float* as1  = (const float*)d_in[8];
  const float* ad1  = (const float*)d_in[9];
  const float* b1   = (const float*)d_in[10];
  const float* W2   = (const float*)d_in[11];
  const float* as2  = (const float*)d_in[12];
  const float* ad2  = (const float*)d_in[13];
  const float* b2   = (const float*)d_in[14];
  const float* bn0g = (const float*)d_in[15];
  const float* bn0b = (const float*)d_in[16];
  const float* bn1g = (const float*)d_in[17];
  const float* bn1b = (const float*)d_in[18];
  const float* bn2g = (const float*)d_in[19];
  const float* bn2b = (const float*)d_in[20];
  const float* lng  = (const float*)d_in[21];
  const float* lnb  = (const float*)d_in[22];
  const float* fc1w = (const float*)d_in[23];
  const float* fc1b = (const float*)d_in[24];
  const float* fc2w = (const float*)d_in[25];
  const float* fc2b = (const float*)d_in[26];
  float* out = (float*)d_out;

  char* w = (char*)d_ws;
  auto alloc = [&](size_t bytes) -> char* {
    char* p = w; w += (bytes + 255) & ~(size_t)255; return p;
  };
  __bf16* xb0   = (__bf16*)alloc((size_t)NODES*DIN*2);
  __bf16* hbuf  = (__bf16*)alloc((size_t)NODES*512*2);
  __bf16* gbuf  = (__bf16*)alloc((size_t)NODES*512*2);
  __bf16* x1b   = (__bf16*)alloc((size_t)NODES*512*2);
  __bf16* x2b   = (__bf16*)alloc((size_t)NODES*512*2);
  __bf16* Wt0   = (__bf16*)alloc((size_t)TW0*2);
  __bf16* Wt1   = (__bf16*)alloc((size_t)TW1*2);
  __bf16* Wt2   = (__bf16*)alloc((size_t)TW2*2);
  float*  ssrc  = (float*)alloc((size_t)NODES*8*4);
  float*  sdst  = (float*)alloc((size_t)NODES*8*4);
  int*    rowptr= (int*)alloc((NODES+1)*4);
  int*    colA  = (int*)alloc((size_t)ETOT*4);
  float*  partial=(float*)alloc((size_t)2*512*512*4);
  float*  sum0  = (float*)alloc(512*4);
  float*  sq0   = (float*)alloc(512*4);
  float*  sum1  = (float*)alloc(512*4);
  float*  sq1   = (float*)alloc(512*4);
  float*  sum2  = (float*)alloc(64*4);
  float*  sq2   = (float*)alloc(64*4);
  char* zbase  = w;
  int*   deg   = (int*)alloc(NODES*4);
  int*   cursor= (int*)alloc(NODES*4);
  float* pooled= (float*)alloc(NGRAPH*DH*4);   // zero-initialized (atomic accumulation)
  size_t zbytes = (size_t)(w - zbase);
  hipMemsetAsync(zbase, 0, zbytes, stream);

  const int prep_total = PREPW + ETOT;
  k_prep<<<(prep_total + 255)/256, 256, 0, stream>>>(x, xb0, W0, W1, W2, Wt0, Wt1, Wt2, ei, deg);
  k_scan<<<1, 1024, 0, stream>>>(deg, rowptr);
  const int eb = (ETOT + 255)/256;
  k_fill<<<eb, 256, 0, stream>>>(ei, rowptr, cursor, colA);

  const int mb128 = (NODES + 127)/128;
  const int nb8 = (NODES + 7)/8;
  const int nb16 = (NODES + 15)/16;

  // ---- layer 0: 256 -> 8x64 ----
  k_gemm_bf16<<<dim3(4, mb128), 256, 0, stream>>>(xb0, Wt0, hbuf, as0, ad0, ssrc, sdst, 8, NODES, 512, DIN);
  k_gatagg8<<<NODES, 512, 0, stream>>>(hbuf, ssrc, sdst, rowptr, colA, b0, gbuf);
  k_bnstat1<<<512, 256, 0, stream>>>(gbuf, partial, 512);
  k_bnstat2<<<1024, 64, 0, stream>>>(partial, sum0, sq0, 512, 512);
  k_bnapply_b<<<nb16, 256, 0, stream>>>(gbuf, sum0, sq0, bn0g, bn0b, nullptr, x1b, 16);

  // ---- layer 1: 512 -> 8x64, residual ----
  k_gemm_bf16<<<dim3(4, mb128), 256, 0, stream>>>(x1b, Wt1, hbuf, as1, ad1, ssrc, sdst, 8, NODES, 512, 512);
  k_gatagg8<<<NODES, 512, 0, stream>>>(hbuf, ssrc, sdst, rowptr, colA, b1, gbuf);
  k_bnstat1<<<512, 256, 0, stream>>>(gbuf, partial, 512);
  k_bnstat2<<<1024, 64, 0, stream>>>(partial, sum1, sq1, 512, 512);
  k_bnapply_b<<<nb16, 256, 0, stream>>>(gbuf, sum1, sq1, bn1g, bn1b, x1b, x2b, 16);

  // ---- layer 2: 512 -> 1x64 ----
  k_gemm_bf16<<<dim3(1, mb128), 256, 0, stream>>>(x2b, Wt2, hbuf, as2, ad2, ssrc, sdst, 1, NODES, 64, 512);
  k_gatagg1<<<NODES, 256, 0, stream>>>(hbuf, ssrc, sdst, rowptr, colA, b2, gbuf);
  k_bnstat1<<<256, 256, 0, stream>>>(gbuf, partial, 64);
  k_bnstat2<<<128, 64, 0, stream>>>(partial, sum2, sq2, 64, 256);
  k_bn_elu_ln_pool<<<nb8, 256, 0, stream>>>(gbuf, sum2, sq2, bn2g, bn2b, lng, lnb, batch, pooled);

  k_head<<<1, 32, 0, stream>>>(pooled, batch, fc1w, fc1b, fc2w, fc2b, out);
}

// Round 14
// 688.773 us; speedup vs baseline: 1.1221x; 1.1221x over previous
//
#include <hip/hip_runtime.h>
#include <math.h>

#define NODES 30000
#define NEDGE 480000
#define ETOT  (NODES + NEDGE)
#define NGRAPH 30
#define DIN 256
#define DH 64
#define CAP 128

typedef __bf16 bf16x8 __attribute__((ext_vector_type(8)));
typedef float  f32x4  __attribute__((ext_vector_type(4)));

static __device__ __forceinline__ float elu_f(float x){ return x > 0.f ? x : expm1f(x); }
static __device__ __forceinline__ float bf_lo(unsigned v){ return __uint_as_float(v << 16); }
static __device__ __forceinline__ float bf_hi(unsigned v){ return __uint_as_float(v & 0xffff0000u); }
static __device__ __forceinline__ unsigned pack_bf2(float a, float b){
  __bf16 ob[2] = {(__bf16)a, (__bf16)b};
  return *(unsigned*)ob;
}
static __device__ __forceinline__ void load_lds16(const __bf16* g, __bf16* l){
  __builtin_amdgcn_global_load_lds(
      (const __attribute__((address_space(1))) void*)g,
      (__attribute__((address_space(3))) void*)l, 16, 0, 0);
}

// ---------------- CSR: scan + fill (count fused into k_prep) ----------------
__global__ void k_scan(const int* __restrict__ deg, int* __restrict__ rowptr){
  __shared__ int s[1024];
  int t = threadIdx.x;
  const int CH = (NODES + 1023) / 1024;
  int base = t * CH;
  int local = 0;
  for (int i = 0; i < CH; i++){ int idx = base + i; if (idx < NODES) local += deg[idx]; }
  s[t] = local; __syncthreads();
  for (int off = 1; off < 1024; off <<= 1){
    int v = (t >= off) ? s[t - off] : 0;
    __syncthreads();
    s[t] += v;
    __syncthreads();
  }
  int run = s[t] - local;
  for (int i = 0; i < CH; i++){
    int idx = base + i;
    if (idx < NODES){ rowptr[idx] = run; run += deg[idx]; }
  }
  if (t == 1023) rowptr[NODES] = s[1023];
}

__global__ void k_fill(const int* __restrict__ ei, const int* __restrict__ rowptr,
                       int* __restrict__ cursor, int* __restrict__ colA){
  int e = blockIdx.x*256 + threadIdx.x;
  if (e >= ETOT) return;
  int src, dst;
  if (e < NEDGE){ src = ei[e]; dst = ei[NEDGE + e]; }
  else          { src = e - NEDGE; dst = src; }
  int pos = atomicAdd(&cursor[dst], 1);
  colA[rowptr[dst] + pos] = src;
}

// ---------------- fused: input cast + weight transposes + edge degree count ----------------
#define NCAST4 (NODES*DIN/4)
#define TW0 (512*256)
#define TW1 (512*512)
#define TW2 (64*512)
#define PREPW (NCAST4 + TW0 + TW1 + TW2)
__global__ void k_prep(const float* __restrict__ x, __bf16* __restrict__ xb0,
                       const float* __restrict__ W0, const float* __restrict__ W1,
                       const float* __restrict__ W2, __bf16* __restrict__ Wt0,
                       __bf16* __restrict__ Wt1, __bf16* __restrict__ Wt2,
                       const int* __restrict__ ei, int* __restrict__ deg){
  int idx = blockIdx.x*256 + threadIdx.x;
  if (idx < NCAST4){
    float4 v = ((const float4*)x)[idx];
    __bf16 o[4] = {(__bf16)v.x, (__bf16)v.y, (__bf16)v.z, (__bf16)v.w};
    *(uint2*)(xb0 + (size_t)idx*4) = *(const uint2*)o;
    return;
  }
  int j = idx - NCAST4;
  if (j < TW0){
    int n = j >> 8, k = j & 255;
    Wt0[j] = (__bf16)W0[(size_t)k*512 + n];
    return;
  }
  j -= TW0;
  if (j < TW1){
    int n = j >> 9, k = j & 511;
    Wt1[j] = (__bf16)W1[(size_t)k*512 + n];
    return;
  }
  j -= TW1;
  if (j < TW2){
    int n = j >> 9, k = j & 511;
    Wt2[j] = (__bf16)W2[(size_t)k*64 + n];
    return;
  }
  j -= TW2;
  if (j < ETOT){
    int dst = (j < NEDGE) ? ei[NEDGE + j] : (j - NEDGE);
    atomicAdd(&deg[dst], 1);
  }
}

// ---------------- bf16 MFMA GEMM (global_load_lds staging) + fused attention scores ----------------
__global__ __launch_bounds__(256) void k_gemm_bf16(const __bf16* __restrict__ A,
    const __bf16* __restrict__ Bt, __bf16* __restrict__ C,
    const float* __restrict__ asrc, const float* __restrict__ adst,
    float* __restrict__ ssrc, float* __restrict__ sdst, int heads,
    int M, int N, int K){
  __shared__ __align__(16) __bf16 As[128*64];
  __shared__ __align__(16) __bf16 Bs[128*64];
  int tid  = threadIdx.x;
  int lane = tid & 63, wave = tid >> 6;
  int wr = wave >> 1, wc = wave & 1;
  int q = lane >> 4, r = lane & 15;
  int rowBase = blockIdx.y * 128, colBase = blockIdx.x * 128;
  f32x4 acc[4][4] = {};
  for (int k0 = 0; k0 < K; k0 += 64){
    #pragma unroll
    for (int p = 0; p < 4; p++){
      int lin = p*256 + tid;
      int rr = lin >> 3, ko = (lin & 7) * 8;
      int gr = rowBase + rr; if (gr >= M) gr = M - 1;
      load_lds16(A + (size_t)gr*K + k0 + ko, As + lin*8);
      int gn = colBase + rr; if (gn >= N) gn = N - 1;
      load_lds16(Bt + (size_t)gn*K + k0 + ko, Bs + lin*8);
    }
    __syncthreads();
    #pragma unroll
    for (int kk = 0; kk < 2; kk++){
      bf16x8 af[4], bfr[4];
      #pragma unroll
      for (int i = 0; i < 4; i++) af[i]  = *(const bf16x8*)(&As[(wr*64 + i*16 + r)*64 + kk*32 + q*8]);
      #pragma unroll
      for (int j = 0; j < 4; j++) bfr[j] = *(const bf16x8*)(&Bs[(wc*64 + j*16 + r)*64 + kk*32 + q*8]);
      #pragma unroll
      for (int i = 0; i < 4; i++)
        #pragma unroll
        for (int j = 0; j < 4; j++)
          acc[i][j] = __builtin_amdgcn_mfma_f32_16x16x32_bf16(af[i], bfr[j], acc[i][j], 0, 0, 0);
    }
    __syncthreads();
  }
  #pragma unroll
  for (int i = 0; i < 4; i++){
    #pragma unroll
    for (int j = 0; j < 4; j++){
      int col = colBase + wc*64 + j*16 + r;
      if (col >= N) continue;
      #pragma unroll
      for (int v = 0; v < 4; v++){
        int row = rowBase + wr*64 + i*16 + q*4 + v;
        if (row < M) C[(size_t)row*N + col] = (__bf16)acc[i][j][v];
      }
    }
  }
  // fused attention scores
  int colW = colBase + wc*64;
  if (colW < N){
    int hb = colW >> 6;
    float a_s[4], a_d[4];
    #pragma unroll
    for (int j = 0; j < 4; j++){
      a_s[j] = asrc[hb*64 + j*16 + r];
      a_d[j] = adst[hb*64 + j*16 + r];
    }
    #pragma unroll
    for (int i = 0; i < 4; i++){
      #pragma unroll
      for (int v = 0; v < 4; v++){
        float s1 = 0.f, s2 = 0.f;
        #pragma unroll
        for (int j = 0; j < 4; j++){
          float av = acc[i][j][v];
          s1 += av * a_s[j];
          s2 += av * a_d[j];
        }
        #pragma unroll
        for (int off = 1; off < 16; off <<= 1){
          s1 += __shfl_xor(s1, off, 64);
          s2 += __shfl_xor(s2, off, 64);
        }
        if (r == 0){
          int row = rowBase + wr*64 + i*16 + q*4 + v;
          if (row < M){
            ssrc[(size_t)row*heads + hb] = s1;
            sdst[(size_t)row*heads + hb] = s2;
          }
        }
      }
    }
  }
}

// ---------------- GAT aggregation, 8 heads; 8 feats/thread (uint4), 4 edge-waves, unroll-4 ----------------
__global__ __launch_bounds__(256) void k_gatagg8(const __bf16* __restrict__ hb,
    const float* __restrict__ ssrc, const float* __restrict__ sdst,
    const int* __restrict__ rowptr, const int* __restrict__ colA,
    const float* __restrict__ bias, __bf16* __restrict__ outb){
  int n = blockIdx.x;
  int t = threadIdx.x;
  __shared__ int ecol[CAP];
  __shared__ float p[CAP][9];
  __shared__ float racc[3][8][64];
  __shared__ float dhv[8], sdsh[8], mh[8];
  int base = rowptr[n];
  int deg = rowptr[n+1] - base;
  if (t < 8) sdsh[t] = sdst[(size_t)n*8 + t];
  __syncthreads();
  int g = t >> 5, l32 = t & 31;
  int quar = t >> 6, l = t & 63;
  int f8 = l * 8;
  int hh = l >> 3;
  if (deg <= CAP){
    if (t < deg){
      int c = colA[base + t];
      ecol[t] = c;
      const float4* sp = (const float4*)(ssrc + (size_t)c*8);
      float4 s0 = sp[0], s1 = sp[1];
      float v;
      v = s0.x + sdsh[0]; p[t][0] = v > 0.f ? v : 0.2f*v;
      v = s0.y + sdsh[1]; p[t][1] = v > 0.f ? v : 0.2f*v;
      v = s0.z + sdsh[2]; p[t][2] = v > 0.f ? v : 0.2f*v;
      v = s0.w + sdsh[3]; p[t][3] = v > 0.f ? v : 0.2f*v;
      v = s1.x + sdsh[4]; p[t][4] = v > 0.f ? v : 0.2f*v;
      v = s1.y + sdsh[5]; p[t][5] = v > 0.f ? v : 0.2f*v;
      v = s1.z + sdsh[6]; p[t][6] = v > 0.f ? v : 0.2f*v;
      v = s1.w + sdsh[7]; p[t][7] = v > 0.f ? v : 0.2f*v;
    }
    __syncthreads();
    {
      float m = -1e30f;
      for (int e = l32; e < deg; e += 32) m = fmaxf(m, p[e][g]);
      #pragma unroll
      for (int off = 1; off < 32; off <<= 1) m = fmaxf(m, __shfl_xor(m, off, 64));
      float d = 0.f;
      for (int e = l32; e < deg; e += 32){ float xv = __expf(p[e][g] - m); p[e][g] = xv; d += xv; }
      #pragma unroll
      for (int off = 1; off < 32; off <<= 1) d += __shfl_xor(d, off, 64);
      if (l32 == 0) dhv[g] = 1.f / (d + 1e-16f);
    }
    __syncthreads();
    float a0[8] = {}, a1[8] = {};
    int e = quar;
    for (; e + 12 < deg; e += 16){
      int c0 = ecol[e], c1 = ecol[e+4], c2 = ecol[e+8], c3 = ecol[e+12];
      float p0 = p[e][hh], p1 = p[e+4][hh], p2 = p[e+8][hh], p3 = p[e+12][hh];
      uint4 v0 = *(const uint4*)(hb + (size_t)c0*512 + f8);
      uint4 v1 = *(const uint4*)(hb + (size_t)c1*512 + f8);
      uint4 v2 = *(const uint4*)(hb + (size_t)c2*512 + f8);
      uint4 v3 = *(const uint4*)(hb + (size_t)c3*512 + f8);
      unsigned w0[4] = {v0.x, v0.y, v0.z, v0.w};
      unsigned w1[4] = {v1.x, v1.y, v1.z, v1.w};
      unsigned w2[4] = {v2.x, v2.y, v2.z, v2.w};
      unsigned w3[4] = {v3.x, v3.y, v3.z, v3.w};
      #pragma unroll
      for (int j = 0; j < 4; j++){
        a0[2*j]   += p0*bf_lo(w0[j]); a0[2*j+1] += p0*bf_hi(w0[j]);
        a1[2*j]   += p1*bf_lo(w1[j]); a1[2*j+1] += p1*bf_hi(w1[j]);
        a0[2*j]   += p2*bf_lo(w2[j]); a0[2*j+1] += p2*bf_hi(w2[j]);
        a1[2*j]   += p3*bf_lo(w3[j]); a1[2*j+1] += p3*bf_hi(w3[j]);
      }
    }
    for (; e + 4 < deg; e += 8){
      float pe0 = p[e][hh], pe1 = p[e+4][hh];
      uint4 v0 = *(const uint4*)(hb + (size_t)ecol[e]*512 + f8);
      uint4 v1 = *(const uint4*)(hb + (size_t)ecol[e+4]*512 + f8);
      unsigned w0[4] = {v0.x, v0.y, v0.z, v0.w};
      unsigned w1[4] = {v1.x, v1.y, v1.z, v1.w};
      #pragma unroll
      for (int j = 0; j < 4; j++){
        a0[2*j]   += pe0*bf_lo(w0[j]); a0[2*j+1] += pe0*bf_hi(w0[j]);
        a1[2*j]   += pe1*bf_lo(w1[j]); a1[2*j+1] += pe1*bf_hi(w1[j]);
      }
    }
    for (; e < deg; e += 4){
      float pe = p[e][hh];
      uint4 v = *(const uint4*)(hb + (size_t)ecol[e]*512 + f8);
      unsigned w[4] = {v.x, v.y, v.z, v.w};
      #pragma unroll
      for (int j = 0; j < 4; j++){
        a0[2*j] += pe*bf_lo(w[j]); a0[2*j+1] += pe*bf_hi(w[j]);
      }
    }
    #pragma unroll
    for (int j = 0; j < 8; j++) a0[j] += a1[j];
    if (quar){
      #pragma unroll
      for (int j = 0; j < 8; j++) racc[quar-1][j][l] = a0[j];
    }
    __syncthreads();
    if (quar == 0){
      float rcp = dhv[hh];
      float4 bb0 = *(const float4*)(bias + f8);
      float4 bb1 = *(const float4*)(bias + f8 + 4);
      float bb[8] = {bb0.x, bb0.y, bb0.z, bb0.w, bb1.x, bb1.y, bb1.z, bb1.w};
      __bf16 ob[8];
      #pragma unroll
      for (int j = 0; j < 8; j++){
        float s = a0[j] + racc[0][j][l] + racc[1][j][l] + racc[2][j][l];
        ob[j] = (__bf16)(s*rcp + bb[j]);
      }
      *(uint4*)(outb + (size_t)n*512 + f8) = *(const uint4*)ob;
    }
  } else {
    // slow path (deg > CAP; statistically never hit)
    float m = -1e30f;
    for (int e = l32; e < deg; e += 32){
      int c = colA[base + e];
      float sc = ssrc[(size_t)c*8 + g] + sdsh[g];
      sc = sc > 0.f ? sc : 0.2f*sc;
      m = fmaxf(m, sc);
    }
    #pragma unroll
    for (int off = 1; off < 32; off <<= 1) m = fmaxf(m, __shfl_xor(m, off, 64));
    if (l32 == 0) mh[g] = m;
    __syncthreads();
    float d = 0.f;
    float mm = mh[g];
    for (int e = l32; e < deg; e += 32){
      int c = colA[base + e];
      float sc = ssrc[(size_t)c*8 + g] + sdsh[g];
      sc = sc > 0.f ? sc : 0.2f*sc;
      d += __expf(sc - mm);
    }
    #pragma unroll
    for (int off = 1; off < 32; off <<= 1) d += __shfl_xor(d, off, 64);
    if (l32 == 0) dhv[g] = 1.f / (d + 1e-16f);
    __syncthreads();
    float a0[8] = {};
    float mhh = mh[hh];
    float sdd = sdsh[hh];
    for (int e = quar; e < deg; e += 4){
      int c = colA[base + e];
      float sc = ssrc[(size_t)c*8 + hh] + sdd;
      sc = sc > 0.f ? sc : 0.2f*sc;
      float pe = __expf(sc - mhh);
      uint4 v = *(const uint4*)(hb + (size_t)c*512 + f8);
      unsigned w[4] = {v.x, v.y, v.z, v.w};
      #pragma unroll
      for (int j = 0; j < 4; j++){
        a0[2*j] += pe*bf_lo(w[j]); a0[2*j+1] += pe*bf_hi(w[j]);
      }
    }
    if (quar){
      #pragma unroll
      for (int j = 0; j < 8; j++) racc[quar-1][j][l] = a0[j];
    }
    __syncthreads();
    if (quar == 0){
      float rcp = dhv[hh];
      float4 bb0 = *(const float4*)(bias + f8);
      float4 bb1 = *(const float4*)(bias + f8 + 4);
      float bb[8] = {bb0.x, bb0.y, bb0.z, bb0.w, bb1.x, bb1.y, bb1.z, bb1.w};
      __bf16 ob[8];
      #pragma unroll
      for (int j = 0; j < 8; j++){
        float s = a0[j] + racc[0][j][l] + racc[1][j][l] + racc[2][j][l];
        ob[j] = (__bf16)(s*rcp + bb[j]);
      }
      *(uint4*)(outb + (size_t)n*512 + f8) = *(const uint4*)ob;
    }
  }
}

// ---------------- GAT aggregation, 1 head (F=64), bf16 in/out, unroll-2 ----------------
__global__ __launch_bounds__(256) void k_gatagg1(const __bf16* __restrict__ hb,
    const float* __restrict__ ssrc, const float* __restrict__ sdst,
    const int* __restrict__ rowptr, const int* __restrict__ colA,
    const float* __restrict__ bias, __bf16* __restrict__ outb){
  int n = blockIdx.x;
  int t = threadIdx.x;
  __shared__ int ecol[CAP];
  __shared__ float p[CAP];
  __shared__ float racc[8][64];
  __shared__ float dhv1, mh1, sds;
  int base = rowptr[n];
  int deg = rowptr[n+1] - base;
  if (t == 0) sds = sdst[n];
  __syncthreads();
  int g = t >> 5, l = t & 31;
  if (deg <= CAP){
    if (t < deg){
      int c = colA[base + t];
      ecol[t] = c;
      float sc = ssrc[c] + sds;
      p[t] = sc > 0.f ? sc : 0.2f*sc;
    }
    __syncthreads();
    if (t < 64){
      float m = -1e30f;
      for (int e = t; e < deg; e += 64) m = fmaxf(m, p[e]);
      #pragma unroll
      for (int off = 1; off < 64; off <<= 1) m = fmaxf(m, __shfl_xor(m, off, 64));
      float d = 0.f;
      for (int e = t; e < deg; e += 64){ float xv = __expf(p[e] - m); p[e] = xv; d += xv; }
      #pragma unroll
      for (int off = 1; off < 64; off <<= 1) d += __shfl_xor(d, off, 64);
      if (t == 0) dhv1 = 1.f / (d + 1e-16f);
    }
    __syncthreads();
    float a0 = 0.f, a1 = 0.f, b0v = 0.f, b1v = 0.f;
    int e = g;
    for (; e + 8 < deg; e += 16){
      int c0 = ecol[e], c1 = ecol[e+8];
      float pe0 = p[e], pe1 = p[e+8];
      unsigned v0 = *(const unsigned*)(hb + (size_t)c0*64 + l*2);
      unsigned v1 = *(const unsigned*)(hb + (size_t)c1*64 + l*2);
      a0  += pe0*bf_lo(v0); a1  += pe0*bf_hi(v0);
      b0v += pe1*bf_lo(v1); b1v += pe1*bf_hi(v1);
    }
    for (; e < deg; e += 8){
      float pe = p[e];
      unsigned v = *(const unsigned*)(hb + (size_t)ecol[e]*64 + l*2);
      a0 += pe*bf_lo(v); a1 += pe*bf_hi(v);
    }
    a0 += b0v; a1 += b1v;
    racc[g][l*2] = a0; racc[g][l*2+1] = a1;
    __syncthreads();
    if (t < 32){
      float s0 = 0.f, s1 = 0.f;
      #pragma unroll
      for (int g2 = 0; g2 < 8; g2++){ s0 += racc[g2][t*2]; s1 += racc[g2][t*2+1]; }
      float rcp = dhv1;
      float o0 = s0*rcp + bias[t*2], o1 = s1*rcp + bias[t*2+1];
      *(unsigned*)(outb + (size_t)n*64 + t*2) = pack_bf2(o0, o1);
    }
  } else {
    if (t < 64){
      float m = -1e30f;
      for (int e = t; e < deg; e += 64){
        int c = colA[base + e];
        float sc = ssrc[c] + sds;
        sc = sc > 0.f ? sc : 0.2f*sc;
        m = fmaxf(m, sc);
      }
      #pragma unroll
      for (int off = 1; off < 64; off <<= 1) m = fmaxf(m, __shfl_xor(m, off, 64));
      if (t == 0) mh1 = m;
    }
    __syncthreads();
    if (t < 64){
      float d = 0.f;
      for (int e = t; e < deg; e += 64){
        int c = colA[base + e];
        float sc = ssrc[c] + sds;
        sc = sc > 0.f ? sc : 0.2f*sc;
        d += __expf(sc - mh1);
      }
      #pragma unroll
      for (int off = 1; off < 64; off <<= 1) d += __shfl_xor(d, off, 64);
      if (t == 0) dhv1 = 1.f / (d + 1e-16f);
    }
    __syncthreads();
    float a0 = 0.f, a1 = 0.f;
    float mm = mh1;
    for (int e = g; e < deg; e += 8){
      int c = colA[base + e];
      float sc = ssrc[c] + sds;
      sc = sc > 0.f ? sc : 0.2f*sc;
      float pe = __expf(sc - mm);
      unsigned v = *(const unsigned*)(hb + (size_t)c*64 + l*2);
      a0 += pe*bf_lo(v); a1 += pe*bf_hi(v);
    }
    racc[g][l*2] = a0; racc[g][l*2+1] = a1;
    __syncthreads();
    if (t < 32){
      float s0 = 0.f, s1 = 0.f;
      #pragma unroll
      for (int g2 = 0; g2 < 8; g2++){ s0 += racc[g2][t*2]; s1 += racc[g2][t*2+1]; }
      float rcp = dhv1;
      float o0 = s0*rcp + bias[t*2], o1 = s1*rcp + bias[t*2+1];
      *(unsigned*)(outb + (size_t)n*64 + t*2) = pack_bf2(o0, o1);
    }
  }
}

// ---------------- BatchNorm stats, two-stage, NO atomics ----------------
__global__ __launch_bounds__(256) void k_bnstat1(const __bf16* __restrict__ xb,
    float* __restrict__ partial, int F){
  int t = threadIdx.x;
  int OCT = F >> 3;
  int RPB = 256 / OCT;
  int o = t & (OCT - 1), r = t / OCT;
  int NB = gridDim.x;
  float s[8] = {}, q[8] = {};
  int step = NB * RPB;
  for (int n = blockIdx.x*RPB + r; n < NODES; n += step){
    uint4 v = *(const uint4*)(xb + (size_t)n*F + o*8);
    unsigned vv[4] = {v.x, v.y, v.z, v.w};
    #pragma unroll
    for (int j = 0; j < 4; j++){
      float lo = bf_lo(vv[j]), hi = bf_hi(vv[j]);
      s[2*j]   += lo; q[2*j]   += lo*lo;
      s[2*j+1] += hi; q[2*j+1] += hi*hi;
    }
  }
  __shared__ float red[256][17];
  #pragma unroll
  for (int j = 0; j < 8; j++){ red[t][j] = s[j]; red[t][8+j] = q[j]; }
  __syncthreads();
  for (int st = RPB >> 1; st > 0; st >>= 1){
    if (r < st){
      #pragma unroll
      for (int j = 0; j < 16; j++) red[t][j] += red[t + st*OCT][j];
    }
    __syncthreads();
  }
  if (r == 0){
    #pragma unroll
    for (int j = 0; j < 8; j++){
      partial[(size_t)(o*8 + j)*NB + blockIdx.x]     = red[t][j];
      partial[(size_t)(F + o*8 + j)*NB + blockIdx.x] = red[t][8 + j];
    }
  }
}

__global__ void k_bnstat2(const float* __restrict__ partial, float* __restrict__ sum,
                          float* __restrict__ sumsq, int F, int NB){
  int row = blockIdx.x;
  int t = threadIdx.x;
  float a = 0.f;
  for (int i = t; i < NB; i += 64) a += partial[(size_t)row*NB + i];
  #pragma unroll
  for (int off = 1; off < 64; off <<= 1) a += __shfl_xor(a, off, 64);
  if (t == 0){
    if (row < F) sum[row] = a;
    else         sumsq[row - F] = a;
  }
}

// ---------------- BN(inline) + ELU + optional residual, bf16->bf16, uint4 ----------------
__global__ __launch_bounds__(256) void k_bnapply_b(const __bf16* __restrict__ xb,
    const float* __restrict__ sum, const float* __restrict__ sumsq,
    const float* __restrict__ g, const float* __restrict__ b,
    const __bf16* __restrict__ res, __bf16* __restrict__ y, int rows){
  int t = threadIdx.x;
  int o8 = (t & 63) * 8;
  int rw = t >> 6;
  float sm[8], sq[8], gg[8], bb[8];
  *(float4*)sm     = *(const float4*)(sum + o8);
  *(float4*)(sm+4) = *(const float4*)(sum + o8 + 4);
  *(float4*)sq     = *(const float4*)(sumsq + o8);
  *(float4*)(sq+4) = *(const float4*)(sumsq + o8 + 4);
  *(float4*)gg     = *(const float4*)(g + o8);
  *(float4*)(gg+4) = *(const float4*)(g + o8 + 4);
  *(float4*)bb     = *(const float4*)(b + o8);
  *(float4*)(bb+4) = *(const float4*)(b + o8 + 4);
  const float inv_n = 1.f / (float)NODES;
  float sc[8], sh[8];
  #pragma unroll
  for (int j = 0; j < 8; j++){
    float m = sm[j]*inv_n;
    float v = sq[j]*inv_n - m*m;
    sc[j] = gg[j]*rsqrtf(v + 1e-5f);
    sh[j] = bb[j] - m*sc[j];
  }
  int nend = min(blockIdx.x*rows + rows, NODES);
  for (int n = blockIdx.x*rows + rw; n < nend; n += 4){
    size_t off = (size_t)n*512 + o8;
    uint4 v = *(const uint4*)(xb + off);
    unsigned w[4] = {v.x, v.y, v.z, v.w};
    float ov[8];
    #pragma unroll
    for (int j = 0; j < 4; j++){
      ov[2*j]   = elu_f(bf_lo(w[j])*sc[2*j]   + sh[2*j]);
      ov[2*j+1] = elu_f(bf_hi(w[j])*sc[2*j+1] + sh[2*j+1]);
    }
    if (res){
      uint4 rv = *(const uint4*)(res + off);
      unsigned rw4[4] = {rv.x, rv.y, rv.z, rv.w};
      #pragma unroll
      for (int j = 0; j < 4; j++){
        ov[2*j] += bf_lo(rw4[j]); ov[2*j+1] += bf_hi(rw4[j]);
      }
    }
    __bf16 ob[8];
    #pragma unroll
    for (int j = 0; j < 8; j++) ob[j] = (__bf16)ov[j];
    *(uint4*)(y + off) = *(const uint4*)ob;
  }
}

// ---------------- BN + ELU + LayerNorm (F=64) + fused graph-pool accumulation ----------------
__global__ void k_bn_elu_ln_pool(const __bf16* __restrict__ xb, const float* __restrict__ sum,
    const float* __restrict__ sumsq, const float* __restrict__ g, const float* __restrict__ b,
    const float* __restrict__ lg, const float* __restrict__ lb,
    const int* __restrict__ batch, float* __restrict__ pooled){
  int t = threadIdx.x;
  int l = t & 31, sub = t >> 5;
  int n = blockIdx.x*8 + sub;
  float2 sm = *(const float2*)(sum + l*2);
  float2 sq = *(const float2*)(sumsq + l*2);
  float2 gg = *(const float2*)(g + l*2);
  float2 bb = *(const float2*)(b + l*2);
  const float inv_n = 1.f / (float)NODES;
  float m0 = sm.x*inv_n, m1 = sm.y*inv_n;
  float va0 = sq.x*inv_n - m0*m0, va1 = sq.y*inv_n - m1*m1;
  float sc0 = gg.x * rsqrtf(va0 + 1e-5f), sc1 = gg.y * rsqrtf(va1 + 1e-5f);
  float sh0 = bb.x - m0*sc0, sh1 = bb.y - m1*sc1;
  unsigned v = *(const unsigned*)(xb + (size_t)n*64 + l*2);
  float x0 = elu_f(bf_lo(v)*sc0 + sh0);
  float x1 = elu_f(bf_hi(v)*sc1 + sh1);
  float s = x0 + x1;
  #pragma unroll
  for (int off = 1; off < 32; off <<= 1) s += __shfl_xor(s, off, 64);
  float mean = s * (1.f/64.f);
  float d0 = x0 - mean, d1 = x1 - mean;
  float qq = d0*d0 + d1*d1;
  #pragma unroll
  for (int off = 1; off < 32; off <<= 1) qq += __shfl_xor(qq, off, 64);
  float var = qq * (1.f/64.f);
  float inv = rsqrtf(var + 1e-5f);
  float o0 = d0*inv*lg[l*2] + lb[l*2];
  float o1 = d1*inv*lg[l*2+1] + lb[l*2+1];
  __shared__ float sv[8][64];
  __shared__ int gid[8];
  sv[sub][l*2] = o0; sv[sub][l*2+1] = o1;
  if (l == 0) gid[sub] = batch[n];
  __syncthreads();
  if (t < 64){
    int g0 = gid[0];
    if (gid[7] == g0){
      float acc = 0.f;
      #pragma unroll
      for (int r = 0; r < 8; r++) acc += sv[r][t];
      atomicAdd(&pooled[g0*64 + t], acc);
    } else {
      #pragma unroll
      for (int r = 0; r < 8; r++) atomicAdd(&pooled[gid[r]*64 + t], sv[r][t]);
    }
  }
}

// ---------------- MLP head + log_softmax ----------------
static __device__ int lbound(const int* a, int n, int v){
  int lo = 0, hi = n;
  while (lo < hi){ int mid = (lo + hi) >> 1; if (a[mid] < v) lo = mid + 1; else hi = mid; }
  return lo;
}

__global__ void k_head(const float* __restrict__ pooled, const int* __restrict__ batch,
                       const float* __restrict__ w1, const float* __restrict__ b1,
                       const float* __restrict__ w2, const float* __restrict__ b2,
                       float* __restrict__ out){
  int g = threadIdx.x;
  if (g >= NGRAPH) return;
  int lo = lbound(batch, NODES, g);
  int hi = lbound(batch, NODES, g+1);
  float inv_cnt = 1.f / fmaxf((float)(hi - lo), 1.f);
  float pd[64];
  for (int d = 0; d < 64; d++) pd[d] = pooled[g*DH + d] * inv_cnt;
  float hdd[32];
  for (int j = 0; j < 32; j++){
    float s = b1[j];
    for (int d = 0; d < DH; d++) s += pd[d]*w1[d*32 + j];
    hdd[j] = elu_f(s);
  }
  float l0 = b2[0], l1 = b2[1];
  for (int j = 0; j < 32; j++){ l0 += hdd[j]*w2[j*2]; l1 += hdd[j]*w2[j*2 + 1]; }
  float m = fmaxf(l0, l1);
  float lse = m + logf(expf(l0 - m) + expf(l1 - m));
  out[g*2]     = l0 - lse;
  out[g*2 + 1] = l1 - lse;
}

extern "C" void kernel_launch(void* const* d_in, const int* in_sizes, int n_in,
                              void* d_out, int out_size, void* d_ws, size_t ws_size,
                              hipStream_t stream){
  const float* x    = (const float*)d_in[0];
  const int*   ei   = (const int*)d_in[1];
  const int*   batch= (const int*)d_in[2];
  const float* W0   = (const float*)d_in[3];
  const float* as0  = (const float*)d_in[4];
  const float* ad0  = (const float*)d_in[5];
  const float* b0   = (const float*)d_in[6];
  const float* W1   = (const float*)d_in[7];
  const float* as1  = (const float*)d_in[8];
  const float* ad1  = (const float*)d_in[9];
  const float* b1   = (const float*)d_in[10];
  const float* W2   = (const float*)d_in[11];
  const float* as2  = (const float*)d_in[12];
  const float* ad2  = (const float*)d_in[13];
  const float* b2   = (const float*)d_in[14];
  const float* bn0g = (const float*)d_in[15];
  const float* bn0b = (const float*)d_in[16];
  const float* bn1g = (const float*)d_in[17];
  const float* bn1b = (const float*)d_in[18];
  const float* bn2g = (const float*)d_in[19];
  const float* bn2b = (const float*)d_in[20];
  const float* lng  = (const float*)d_in[21];
  const float* lnb  = (const float*)d_in[22];
  const float* fc1w = (const float*)d_in[23];
  const float* fc1b = (const float*)d_in[24];
  const float* fc2w = (const float*)d_in[25];
  const float* fc2b = (const float*)d_in[26];
  float* out = (float*)d_out;

  char* w = (char*)d_ws;
  auto alloc = [&](size_t bytes) -> char* {
    char* p = w; w += (bytes + 255) & ~(size_t)255; return p;
  };
  __bf16* xb0   = (__bf16*)alloc((size_t)NODES*DIN*2);
  __bf16* hbuf  = (__bf16*)alloc((size_t)NODES*512*2);
  __bf16* gbuf  = (__bf16*)alloc((size_t)NODES*512*2);
  __bf16* x1b   = (__bf16*)alloc((size_t)NODES*512*2);
  __bf16* x2b   = (__bf16*)alloc((size_t)NODES*512*2);
  __bf16* Wt0   = (__bf16*)alloc((size_t)TW0*2);
  __bf16* Wt1   = (__bf16*)alloc((size_t)TW1*2);
  __bf16* Wt2   = (__bf16*)alloc((size_t)TW2*2);
  float*  ssrc  = (float*)alloc((size_t)NODES*8*4);
  float*  sdst  = (float*)alloc((size_t)NODES*8*4);
  int*    rowptr= (int*)alloc((NODES+1)*4);
  int*    colA  = (int*)alloc((size_t)ETOT*4);
  float*  partial=(float*)alloc((size_t)2*512*512*4);
  float*  sum0  = (float*)alloc(512*4);
  float*  sq0   = (float*)alloc(512*4);
  float*  sum1  = (float*)alloc(512*4);
  float*  sq1   = (float*)alloc(512*4);
  float*  sum2  = (float*)alloc(64*4);
  float*  sq2   = (float*)alloc(64*4);
  char* zbase  = w;
  int*   deg   = (int*)alloc(NODES*4);
  int*   cursor= (int*)alloc(NODES*4);
  float* pooled= (float*)alloc(NGRAPH*DH*4);   // zero-initialized (atomic accumulation)
  size_t zbytes = (size_t)(w - zbase);
  hipMemsetAsync(zbase, 0, zbytes, stream);

  const int prep_total = PREPW + ETOT;
  k_prep<<<(prep_total + 255)/256, 256, 0, stream>>>(x, xb0, W0, W1, W2, Wt0, Wt1, Wt2, ei, deg);
  k_scan<<<1, 1024, 0, stream>>>(deg, rowptr);
  const int eb = (ETOT + 255)/256;
  k_fill<<<eb, 256, 0, stream>>>(ei, rowptr, cursor, colA);

  const int mb128 = (NODES + 127)/128;
  const int nb8 = (NODES + 7)/8;
  const int nb16 = (NODES + 15)/16;

  // ---- layer 0: 256 -> 8x64 ----
  k_gemm_bf16<<<dim3(4, mb128), 256, 0, stream>>>(xb0, Wt0, hbuf, as0, ad0, ssrc, sdst, 8, NODES, 512, DIN);
  k_gatagg8<<<NODES, 256, 0, stream>>>(hbuf, ssrc, sdst, rowptr, colA, b0, gbuf);
  k_bnstat1<<<512, 256, 0, stream>>>(gbuf, partial, 512);
  k_bnstat2<<<1024, 64, 0, stream>>>(partial, sum0, sq0, 512, 512);
  k_bnapply_b<<<nb16, 256, 0, stream>>>(gbuf, sum0, sq0, bn0g, bn0b, nullptr, x1b, 16);

  // ---- layer 1: 512 -> 8x64, residual ----
  k_gemm_bf16<<<dim3(4, mb128), 256, 0, stream>>>(x1b, Wt1, hbuf, as1, ad1, ssrc, sdst, 8, NODES, 512, 512);
  k_gatagg8<<<NODES, 256, 0, stream>>>(hbuf, ssrc, sdst, rowptr, colA, b1, gbuf);
  k_bnstat1<<<512, 256, 0, stream>>>(gbuf, partial, 512);
  k_bnstat2<<<1024, 64, 0, stream>>>(partial, sum1, sq1, 512, 512);
  k_bnapply_b<<<nb16, 256, 0, stream>>>(gbuf, sum1, sq1, bn1g, bn1b, x1b, x2b, 16);

  // ---- layer 2: 512 -> 1x64 ----
  k_gemm_bf16<<<dim3(1, mb128), 256, 0, stream>>>(x2b, Wt2, hbuf, as2, ad2, ssrc, sdst, 1, NODES, 64, 512);
  k_gatagg1<<<NODES, 256, 0, stream>>>(hbuf, ssrc, sdst, rowptr, colA, b2, gbuf);
  k_bnstat1<<<256, 256, 0, stream>>>(gbuf, partial, 64);
  k_bnstat2<<<128, 64, 0, stream>>>(partial, sum2, sq2, 64, 256);
  k_bn_elu_ln_pool<<<nb8, 256, 0, stream>>>(gbuf, sum2, sq2, bn2g, bn2b, lng, lnb, batch, pooled);

  k_head<<<1, 32, 0, stream>>>(pooled, batch, fc1w, fc1b, fc2w, fc2b, out);
}